// Round 11
// baseline (22.222 us; speedup 1.0000x reference)
//
#include <hip/hip_runtime.h>
#include <math.h>

namespace {

typedef float f32x2 __attribute__((ext_vector_type(2)));

constexpr int NLAY = 10;
constexpr int NQB  = 4;
constexpr int NB   = 16;
constexpr int HH   = 128;
constexpr int WW   = 128;
constexpr int DI   = HH - 1;           // 127
constexpr int DJ   = WW - 1;           // 127
constexpr int NPATCH = NB * DI * DJ;   // 258064
constexpr int BLK   = 256;
constexpr int GRID  = (NPATCH + BLK - 1) / BLK;   // 1009

// Combined CZ(0,1)*CZ(2,3)*CZ(1,2) sign per basis index (bit3=a,...,bit0=d)
constexpr unsigned SIGNMASK = 0xB848u;

__device__ __forceinline__ float2 cmul(float2 a, float2 b) {
    return make_float2(fmaf(a.x, b.x, -a.y * b.y), fmaf(a.x, b.y, a.y * b.x));
}
__device__ __forceinline__ float2 cadd(float2 a, float2 b) {
    return make_float2(a.x + b.x, a.y + b.y);
}
__device__ __forceinline__ void mm2(float2* D, const float2* A, const float2* B) {
    D[0] = cadd(cmul(A[0], B[0]), cmul(A[1], B[2]));
    D[1] = cadd(cmul(A[0], B[1]), cmul(A[1], B[3]));
    D[2] = cadd(cmul(A[2], B[0]), cmul(A[3], B[2]));
    D[3] = cadd(cmul(A[2], B[1]), cmul(A[3], B[3]));
}

// hardware trig: v_sin_f32/v_cos_f32 take REVOLUTIONS (D = sin(S0*2pi)).
// sin(pi*t) == hwsin(0.5*t). All args used here are within [-0.25, 0.5].
__device__ __forceinline__ float hwsin(float x) { return __builtin_amdgcn_sinf(x); }
__device__ __forceinline__ float hwcos(float x) { return __builtin_amdgcn_cosf(x); }

// packed complex FMA / MUL (validated r5) — used only in the phase-1 butterfly
__device__ __forceinline__ void cfma_pk(f32x2& acc, f32x2 m, f32x2 s) {
    asm("v_pk_fma_f32 %0, %1, %2, %0 op_sel_hi:[0,1,1]\n\t"
        "v_pk_fma_f32 %0, %1, %2, %0 op_sel:[1,1,0] op_sel_hi:[1,0,1] neg_lo:[1,0,0]"
        : "+v"(acc) : "v"(m), "v"(s));
}
__device__ __forceinline__ f32x2 cmul_pk(f32x2 a, f32x2 b) {
    f32x2 c;
    asm("v_pk_mul_f32 %0, %1, %2 op_sel_hi:[0,1]\n\t"
        "v_pk_fma_f32 %0, %1, %2, %0 op_sel:[1,1,0] op_sel_hi:[1,0,1] neg_lo:[1,0,0]"
        : "=&v"(c) : "v"(a), "v"(b));
    return c;
}

// ---- single fused kernel: butterfly M build + 1-patch/thread matvec ----
__global__ __launch_bounds__(256) void qcnn_fused_kernel(
    const float* __restrict__ images,   // [16,128,128,3]
    const float* __restrict__ gates,    // [10,4,3] one-hot
    const float* __restrict__ angles,   // [10,4]
    float* __restrict__ out)            // [16,127,127,4]
{
    __shared__ float4 UgA[NLAY * NQB];   // {U00.re,U00.im,U01.re,U01.im}
    __shared__ float4 UgB[NLAY * NQB];   // {U10.re,U10.im,U11.re,U11.im}
    __shared__ float2 Mf[16][16];        // final M[o][j]

    const int t = threadIdx.x;

    // ---- phase 1a: 40 lanes build gate unitaries (hw trig, revolutions) ----
    if (t < NLAY * NQB) {
        constexpr float INV4PI = 0.0795774715459477f;   // 1/(4*pi): rad*0.5 -> rev
        const float ang = angles[t] * INV4PI;
        const float ax = gates[t * 3 + 0] * ang;
        const float ay = gates[t * 3 + 1] * ang;
        const float az = gates[t * 3 + 2] * ang;
        const float sx = hwsin(ax), cx = hwcos(ax);
        const float sy = hwsin(ay), cy = hwcos(ay);
        const float sz = hwsin(az), cz = hwcos(az);
        float2 RX[4] = {{cx, 0.f}, {0.f, -sx}, {0.f, -sx}, {cx, 0.f}};
        float2 RY[4] = {{cy, 0.f}, {-sy, 0.f}, {sy, 0.f}, {cy, 0.f}};
        float2 RZ[4] = {{cz, -sz}, {0.f, 0.f}, {0.f, 0.f}, {cz, sz}};
        float2 Mt[4], U[4];
        mm2(Mt, RY, RX);
        mm2(U, RZ, Mt);
        UgA[t] = make_float4(U[0].x, U[0].y, U[1].x, U[1].y);
        UgB[t] = make_float4(U[2].x, U[2].y, U[3].x, U[3].y);
    }
    __syncthreads();

    // ---- phase 1b: butterfly columns through the circuit, shfl-based ----
    // thread t: amplitude row o = t&15 of basis column j = t>>4.
    const int o = t & 15, j = t >> 4;
    const float czs = ((SIGNMASK >> o) & 1u) ? -1.f : 1.f;

    f32x2 amp = {(o == j) ? 1.f : 0.f, 0.f};
#pragma unroll 1
    for (int l = 0; l < NLAY; ++l) {
#pragma unroll
        for (int q = 0; q < NQB; ++q) {
            const int mask = 8 >> q;
            const float4 uA = UgA[l * 4 + q];      // uniform b128 broadcast
            const float4 uB = UgB[l * 4 + q];
            const bool b = (o & mask) != 0;
            const f32x2 diag = b ? f32x2{uB.z, uB.w} : f32x2{uA.x, uA.y};
            const f32x2 off  = b ? f32x2{uB.x, uB.y} : f32x2{uA.z, uA.w};
            const f32x2 part = {__shfl_xor(amp.x, mask), __shfl_xor(amp.y, mask)};
            f32x2 na = cmul_pk(diag, amp);
            cfma_pk(na, off, part);
            amp = na;
        }
        amp.x *= czs;
        amp.y *= czs;
    }
    Mf[o][j] = make_float2(amp.x, amp.y);
    __syncthreads();

    // ---- phase 2: ONE patch per thread, plain scalar fmaf matvec ----
    const int gid = blockIdx.x * BLK + t;
    const int n = min(gid, NPATCH - 1);
    const int bimg = n / (DI * DJ);
    const int rem  = n - bimg * (DI * DJ);
    const int pi   = rem / DJ;
    const int pj   = rem - pi * DJ;
    const float* base = images + ((size_t)(bimg * HH + pi) * WW + pj) * 3;

    float d[4][3];
#pragma unroll
    for (int a = 0; a < 2; ++a) {
#pragma unroll
        for (int b = 0; b < 2; ++b) {
            const float* px = base + ((size_t)a * WW + b) * 3;
            d[a * 2 + b][0] = px[0];
            d[a * 2 + b][1] = px[1];
            d[a * 2 + b][2] = px[2];
        }
    }

    float2 S[NQB][2];
#pragma unroll
    for (int q = 0; q < NQB; ++q) {
        const float d0 = d[q][0], d1 = d[q][1], d2 = d[q][2];
        const float aarg = 0.25f * (d0 + d2);
        const float barg = 0.25f * (d2 - d0);
        const float targ = 0.25f * d1;
        const float sa = hwsin(aarg), ca = hwcos(aarg);
        const float sb = hwsin(barg), cb = hwcos(barg);
        const float stt = hwsin(targ), ctt = hwcos(targ);
        S[q][0] = make_float2(ca * ctt, -sa * ctt);
        S[q][1] = make_float2(cb * stt,  sb * stt);
    }

    float2 st[16];
#pragma unroll
    for (int a = 0; a < 2; ++a) {
#pragma unroll
        for (int b = 0; b < 2; ++b) {
            const float2 ab = cmul(S[0][a], S[1][b]);
#pragma unroll
            for (int c = 0; c < 2; ++c) {
                const float2 abc = cmul(ab, S[2][c]);
#pragma unroll
                for (int dd = 0; dd < 2; ++dd) {
                    st[a * 8 + b * 4 + c * 2 + dd] = cmul(abc, S[3][dd]);
                }
            }
        }
    }

    float e0 = 0.f, e1 = 0.f, e2 = 0.f, e3 = 0.f;
    const float4* Mrow = reinterpret_cast<const float4*>(&Mf[0][0]);
#pragma unroll
    for (int oo = 0; oo < 16; ++oo) {
        float ax = 0.f, ay = 0.f;
#pragma unroll
        for (int kk = 0; kk < 8; ++kk) {
            const float4 m = Mrow[oo * 8 + kk];   // uniform LDS broadcast
            const float2 s0 = st[2 * kk];
            const float2 s1 = st[2 * kk + 1];
            ax = fmaf(m.x, s0.x, ax);
            ax = fmaf(-m.y, s0.y, ax);
            ay = fmaf(m.x, s0.y, ay);
            ay = fmaf(m.y, s0.x, ay);
            ax = fmaf(m.z, s1.x, ax);
            ax = fmaf(-m.w, s1.y, ax);
            ay = fmaf(m.z, s1.y, ay);
            ay = fmaf(m.w, s1.x, ay);
        }
        const float pr = fmaf(ax, ax, ay * ay);
        e0 += (oo & 8) ? -pr : pr;
        e1 += (oo & 4) ? -pr : pr;
        e2 += (oo & 2) ? -pr : pr;
        e3 += (oo & 1) ? -pr : pr;
    }

    if (gid < NPATCH) {
        *reinterpret_cast<float4*>(out + (size_t)n * 4) =
            make_float4(e0, e1, e2, e3);
    }
}

}  // namespace

extern "C" void kernel_launch(void* const* d_in, const int* in_sizes, int n_in,
                              void* d_out, int out_size, void* d_ws, size_t ws_size,
                              hipStream_t stream) {
    const float* images = (const float*)d_in[0];
    const float* gates  = (const float*)d_in[1];
    const float* angles = (const float*)d_in[2];
    float* out = (float*)d_out;

    qcnn_fused_kernel<<<GRID, BLK, 0, stream>>>(images, gates, angles, out);
}